// Round 6
// baseline (154.656 us; speedup 1.0000x reference)
//
#include <hip/hip_runtime.h>

#define THREADS 256
#define M_BLOCK 128
#define C_DIM 64
#define K_CODES 1024
#define N_CHUNK 64
#define N_CHUNKS 16

#define QUANT_OFF 0
#define LOSS_OFF  4194304
#define IDX_OFF   4194306

// ws layout (bytes): [0..8) double loss-sum; [64..4160) 0.5*|cb|^2 (1024 f32);
// [8192..401408) B-stream: 16 chunks x 24 segs x 1024 B (bf16, negated splits)
#define WS_CBSQH_F 16
#define WS_STREAM_B 8192
#define CHUNK_BYTES 24576
#define SEG_BYTES 1024
#define WS_NEEDED (WS_STREAM_B + N_CHUNKS * CHUNK_BYTES)

typedef float floatx16 __attribute__((ext_vector_type(16)));
typedef short bf16x8  __attribute__((ext_vector_type(8)));

static __device__ inline unsigned short f2bf(float v) {
    unsigned int u = __float_as_uint(v);
    unsigned int r = (u + 0x7FFF + ((u >> 16) & 1)) >> 16;   // RNE
    return (unsigned short)r;
}
static __device__ inline float bf2f(unsigned short b) {
    return __uint_as_float(((unsigned int)b) << 16);
}

// ---------------- prep: cb -> negated bf16 split stream + 0.5*|cb|^2 ----------------
// grid 400 x 64: blocks 0..383 = (chunk,seg) pairs; 384..399 = cb_sq.
__global__ void vq_prep(const float* __restrict__ cb, float* __restrict__ ws)
{
    const int tid = threadIdx.x;               // 0..63 = lane
    const int blk = blockIdx.x;
    if (blk >= 384) {                          // cb_sq/2: 16 blocks x 64 codes
        int code = (blk - 384) * 64 + tid;
        const float4* row = reinterpret_cast<const float4*>(cb + code * C_DIM);
        float s = 0.f;
        #pragma unroll
        for (int j = 0; j < 16; ++j) {
            float4 v = row[j];
            s = fmaf(v.x, v.x, s); s = fmaf(v.y, v.y, s);
            s = fmaf(v.z, v.z, s); s = fmaf(v.w, v.w, s);
        }
        ws[WS_CBSQH_F + code] = 0.5f * s;
        return;
    }
    const int chunk = blk / 24;                // scalar div (uniform)
    const int seg   = blk - chunk * 24;        // 0..23 = wc*12 + tb*4 + s4
    const int wc = seg / 12;
    const int r12 = seg - wc * 12;
    const int tb = r12 >> 2;
    const int s4 = seg & 3;
    const int code = chunk * N_CHUNK + wc * 32 + (tid & 31);
    const int c0   = s4 * 16 + ((tid >> 5) << 3);
    const float* src = cb + code * C_DIM + c0;
    unsigned short us[8];
    #pragma unroll
    for (int j = 0; j < 8; ++j) {
        float v  = src[j];
        float h  = bf2f(f2bf(v));
        float r1 = v - h;                 // exact
        float m  = bf2f(f2bf(r1));
        float r2 = r1 - m;                // exact
        float sel = (tb == 0) ? h : (tb == 1) ? m : r2;
        us[j] = f2bf(-sel);               // negate: MFMA accumulates -dot
    }
    uint4 o;
    o.x = (unsigned)us[0] | ((unsigned)us[1] << 16);
    o.y = (unsigned)us[2] | ((unsigned)us[3] << 16);
    o.z = (unsigned)us[4] | ((unsigned)us[5] << 16);
    o.w = (unsigned)us[6] | ((unsigned)us[7] << 16);
    *reinterpret_cast<uint4*>((char*)ws + WS_STREAM_B + chunk * CHUNK_BYTES
                              + seg * SEG_BYTES + tid * 16) = o;
}

// ---------------- main (MFMA path, B direct from L2, no main-loop barriers) ----------------
__global__ __launch_bounds__(THREADS, 2) void vq_main(
    const float* __restrict__ x,      // [64][64][32][32]
    const float* __restrict__ cb,     // [1024][64] fp32 (epilogue gather)
    const float* __restrict__ ws_f,   // stream + cbsq
    float* __restrict__ out,
    double* __restrict__ ws_sum)
{
    __shared__ __align__(16) float xs[C_DIM * 130];   // 33.3 KB, persists to epilogue
    __shared__ float cbsqh_s[K_CODES];                // 4 KB
    __shared__ float redv[2][M_BLOCK];
    __shared__ int   redi[2][M_BLOCK];
    __shared__ int   kidx_s[M_BLOCK];

    const int tid  = threadIdx.x;
    const int tok0 = blockIdx.x * M_BLOCK;
    const int b    = tok0 >> 10;
    const int hw0  = tok0 & 1023;

    const int w   = tid >> 6;      // wave 0..3
    const int ln  = tid & 63;
    const int wr  = w >> 1;        // wave row: tokens wr*64..
    const int wc  = w & 1;         // wave col: codes wc*32.. per chunk
    const int l31 = ln & 31;
    const int l5  = ln >> 5;

    // ---- stage x tile [c][token] fp32 + cbsq/2 table ----
    #pragma unroll
    for (int j = 0; j < 32; ++j) {
        int idx = j * 256 + tid;
        int c = idx >> 7, t = idx & 127;
        xs[c * 130 + t] = x[((b * C_DIM + c) << 10) + hw0 + t];
    }
    #pragma unroll
    for (int r = 0; r < 4; ++r) {
        int q = r * 256 + tid;
        cbsqh_s[q] = ws_f[WS_CBSQH_F + q];
    }
    __syncthreads();

    // ---- build A fragments (x split, positive): afrag[mt][term][s4] ----
    // A layout (32x32x16): row = l&31, k = (l>>5)*8 + j
    bf16x8 afrag[2][3][4];
    #pragma unroll
    for (int mt = 0; mt < 2; ++mt) {
        const int token = wr * 64 + mt * 32 + l31;
        #pragma unroll
        for (int s4 = 0; s4 < 4; ++s4) {
            const int cb0 = s4 * 16 + l5 * 8;
            #pragma unroll
            for (int j = 0; j < 8; ++j) {
                float v  = xs[(cb0 + j) * 130 + token];
                float h  = bf2f(f2bf(v));
                float r1 = v - h;                 // exact
                float m  = bf2f(f2bf(r1));
                float r2 = r1 - m;                // exact
                afrag[mt][0][s4][j] = (short)f2bf(h);
                afrag[mt][1][s4][j] = (short)f2bf(m);
                afrag[mt][2][s4][j] = (short)f2bf(r2);
            }
        }
    }
    // no barrier: xs is read-only from here on

    // per-wave B base: addr(ch,t) = wbase + ch*CHUNK_BYTES + t*SEG_BYTES, t = tb*4+s4
    const char* wbase = (const char*)ws_f + WS_STREAM_B + wc * 12 * SEG_BYTES + ln * 16;

    float minv[2][16];
    int   mini[2][16];
    #pragma unroll
    for (int mt = 0; mt < 2; ++mt)
        #pragma unroll
        for (int r = 0; r < 16; ++r) { minv[mt][r] = 3.4e38f; mini[mt][r] = 0; }

    bf16x8 bA[12], bB[12];

    // load chunk 0 into bA
    #pragma unroll
    for (int t = 0; t < 12; ++t)
        bA[t] = *reinterpret_cast<const bf16x8*>(wbase + 0 * CHUNK_BYTES + t * SEG_BYTES);

    #pragma unroll 1
    for (int ch = 0; ch < N_CHUNKS; ch += 2) {
        // prefetch ch+1 into bB
        #pragma unroll
        for (int t = 0; t < 12; ++t)
            bB[t] = *reinterpret_cast<const bf16x8*>(wbase + (ch + 1) * CHUNK_BYTES + t * SEG_BYTES);

        // ---- compute chunk ch from bA ----
        {
            const float h = cbsqh_s[ch * N_CHUNK + wc * 32 + l31];
            floatx16 acc0, acc1;
            #pragma unroll
            for (int r = 0; r < 16; ++r) { acc0[r] = h; acc1[r] = h; }
            #pragma unroll
            for (int tb = 0; tb < 3; ++tb)
                #pragma unroll
                for (int s4 = 0; s4 < 4; ++s4) {
                    bf16x8 bf = bA[tb * 4 + s4];
                    #pragma unroll
                    for (int a = 0; a < 3; ++a)
                        if (a + tb <= 2) {   // 6 products
                            acc0 = __builtin_amdgcn_mfma_f32_32x32x16_bf16(afrag[0][a][s4], bf, acc0, 0, 0, 0);
                            acc1 = __builtin_amdgcn_mfma_f32_32x32x16_bf16(afrag[1][a][s4], bf, acc1, 0, 0, 0);
                        }
                }
            const int idxc = ch * N_CHUNK + wc * 32 + l31;
            #pragma unroll
            for (int r = 0; r < 16; ++r) {
                if (acc0[r] < minv[0][r]) { minv[0][r] = acc0[r]; mini[0][r] = idxc; }
                if (acc1[r] < minv[1][r]) { minv[1][r] = acc1[r]; mini[1][r] = idxc; }
            }
        }

        // prefetch ch+2 into bA (clamped; wasted load on last iter, unused)
        {
            const int pc = (ch + 2 > N_CHUNKS - 1) ? (N_CHUNKS - 1) : (ch + 2);
            #pragma unroll
            for (int t = 0; t < 12; ++t)
                bA[t] = *reinterpret_cast<const bf16x8*>(wbase + pc * CHUNK_BYTES + t * SEG_BYTES);
        }

        // ---- compute chunk ch+1 from bB ----
        {
            const float h = cbsqh_s[(ch + 1) * N_CHUNK + wc * 32 + l31];
            floatx16 acc0, acc1;
            #pragma unroll
            for (int r = 0; r < 16; ++r) { acc0[r] = h; acc1[r] = h; }
            #pragma unroll
            for (int tb = 0; tb < 3; ++tb)
                #pragma unroll
                for (int s4 = 0; s4 < 4; ++s4) {
                    bf16x8 bf = bB[tb * 4 + s4];
                    #pragma unroll
                    for (int a = 0; a < 3; ++a)
                        if (a + tb <= 2) {
                            acc0 = __builtin_amdgcn_mfma_f32_32x32x16_bf16(afrag[0][a][s4], bf, acc0, 0, 0, 0);
                            acc1 = __builtin_amdgcn_mfma_f32_32x32x16_bf16(afrag[1][a][s4], bf, acc1, 0, 0, 0);
                        }
                }
            const int idxc = (ch + 1) * N_CHUNK + wc * 32 + l31;
            #pragma unroll
            for (int r = 0; r < 16; ++r) {
                if (acc0[r] < minv[0][r]) { minv[0][r] = acc0[r]; mini[0][r] = idxc; }
                if (acc1[r] < minv[1][r]) { minv[1][r] = acc1[r]; mini[1][r] = idxc; }
            }
        }
    }

    // ---- butterfly argmin across the 32 lanes of each column group ----
    #pragma unroll
    for (int off = 1; off < 32; off <<= 1) {
        #pragma unroll
        for (int mt = 0; mt < 2; ++mt)
            #pragma unroll
            for (int r = 0; r < 16; ++r) {
                float ov = __shfl_xor(minv[mt][r], off, 64);
                int   oi = __shfl_xor(mini[mt][r], off, 64);
                if (ov < minv[mt][r] || (ov == minv[mt][r] && oi < mini[mt][r])) {
                    minv[mt][r] = ov; mini[mt][r] = oi;
                }
            }
    }
    if (l31 == 0) {
        #pragma unroll
        for (int mt = 0; mt < 2; ++mt)
            #pragma unroll
            for (int r = 0; r < 16; ++r) {
                int row = (r & 3) + ((r >> 2) << 3) + (l5 << 2);  // verified 32x32 C/D map
                int token = wr * 64 + mt * 32 + row;
                redv[wc][token] = minv[mt][r];
                redi[wc][token] = mini[mt][r];
            }
    }
    __syncthreads();

    if (tid < M_BLOCK) {
        float v0 = redv[0][tid]; int i0 = redi[0][tid];
        float v1 = redv[1][tid]; int i1 = redi[1][tid];
        int bi = (v1 < v0 || (v1 == v0 && i1 < i0)) ? i1 : i0;
        kidx_s[tid] = bi;
        out[IDX_OFF + tok0 + tid] = (float)bi;
    }
    __syncthreads();

    // ---- epilogue: quant (STE form) + loss partial; x from LDS (xs intact) ----
    {
        const int i  = tid & (M_BLOCK - 1);
        const int c0 = tid >> 7;
        const int kk = kidx_s[i];
        const float* crow = cb + kk * C_DIM;      // L2-resident gather
        float lsum = 0.f;
        #pragma unroll
        for (int j = 0; j < 32; ++j) {
            int c = c0 * 32 + j;
            float q  = crow[c];
            float xv = xs[c * 130 + i];
            float d  = q - xv;                    // (quant - xt)
            lsum = fmaf(d, d, lsum);
            out[QUANT_OFF + ((b * C_DIM + c) << 10) + hw0 + i] = xv + d;  // xt + sg(q-x)
        }
        #pragma unroll
        for (int off = 32; off > 0; off >>= 1)
            lsum += __shfl_down(lsum, off, 64);
        if ((tid & 63) == 0)
            atomicAdd(ws_sum, (double)lsum);
    }
}

// ---------------- fallback (round-2-verified VALU path, used if ws too small) ----------------
#define CB_PAD 68
__global__ __launch_bounds__(THREADS, 2) void vq_main_valu(
    const float* __restrict__ x,
    const float* __restrict__ cb,
    float* __restrict__ out,
    double* __restrict__ ws_sum)
{
    __shared__ float xt_s[C_DIM][M_BLOCK];
    __shared__ float cb_s[C_DIM][CB_PAD];
    __shared__ float cbsq_all[K_CODES];
    __shared__ float red_v[8][M_BLOCK];
    __shared__ int   red_i[8][M_BLOCK];
    __shared__ int   kidx_s[M_BLOCK];

    const int tid  = threadIdx.x;
    const int tok0 = blockIdx.x * M_BLOCK;
    const int b_img = tok0 >> 10;
    const int hw0   = tok0 & 1023;

    #pragma unroll
    for (int r = 0; r < 4; ++r) {
        int k = tid + r * THREADS;
        const float4* row = reinterpret_cast<const float4*>(cb + k * C_DIM);
        float s = 0.f;
        #pragma unroll
        for (int j = 0; j < 16; ++j) {
            float4 v = row[j];
            s = fmaf(v.x, v.x, s); s = fmaf(v.y, v.y, s);
            s = fmaf(v.z, v.z, s); s = fmaf(v.w, v.w, s);
        }
        cbsq_all[k] = s;
    }
    {
        const int i  = tid & (M_BLOCK - 1);
        const int c0 = tid >> 7;
        #pragma unroll
        for (int j = 0; j < 32; ++j) {
            int c = c0 + 2 * j;
            xt_s[c][i] = x[((b_img * C_DIM + c) << 10) + hw0 + i];
        }
    }

    const int tl = tid & 31;
    const int kg = tid >> 5;
    float minv[4]; int mini[4];
    #pragma unroll
    for (int m = 0; m < 4; ++m) { minv[m] = 3.4e38f; mini[m] = 0; }

    for (int ch = 0; ch < 16; ++ch) {
        __syncthreads();
        for (int t = tid; t < 64 * C_DIM; t += THREADS) {
            int kl = t >> 6, c = t & 63;
            cb_s[c][kl] = cb[(ch * 64 + kl) * C_DIM + c];
        }
        __syncthreads();
        float dot[4][8];
        #pragma unroll
        for (int m = 0; m < 4; ++m)
            #pragma unroll
            for (int k = 0; k < 8; ++k) dot[m][k] = 0.f;
        #pragma unroll 4
        for (int c = 0; c < C_DIM; ++c) {
            float4 xv  = *reinterpret_cast<const float4*>(&xt_s[c][tl * 4]);
            float4 cv0 = *reinterpret_cast<const float4*>(&cb_s[c][kg * 8]);
            float4 cv1 = *reinterpret_cast<const float4*>(&cb_s[c][kg * 8 + 4]);
            float xa[4] = {xv.x, xv.y, xv.z, xv.w};
            float ca[8] = {cv0.x, cv0.y, cv0.z, cv0.w, cv1.x, cv1.y, cv1.z, cv1.w};
            #pragma unroll
            for (int m = 0; m < 4; ++m)
                #pragma unroll
                for (int k = 0; k < 8; ++k)
                    dot[m][k] = fmaf(xa[m], ca[k], dot[m][k]);
        }
        const int codebase = ch * 64 + kg * 8;
        #pragma unroll
        for (int k = 0; k < 8; ++k) {
            float csq = cbsq_all[codebase + k];
            #pragma unroll
            for (int m = 0; m < 4; ++m) {
                float sc = fmaf(-2.f, dot[m][k], csq);
                if (sc < minv[m]) { minv[m] = sc; mini[m] = codebase + k; }
            }
        }
    }
    #pragma unroll
    for (int m = 0; m < 4; ++m) {
        red_v[kg][tl * 4 + m] = minv[m];
        red_i[kg][tl * 4 + m] = mini[m];
    }
    __syncthreads();
    if (tid < M_BLOCK) {
        float bv = red_v[0][tid]; int bi = red_i[0][tid];
        #pragma unroll
        for (int g = 1; g < 8; ++g) {
            float v = red_v[g][tid]; int ii = red_i[g][tid];
            if (v < bv || (v == bv && ii < bi)) { bv = v; bi = ii; }
        }
        kidx_s[tid] = bi;
        out[IDX_OFF + tok0 + tid] = (float)bi;
    }
    __syncthreads();
    {
        const int i  = tid & (M_BLOCK - 1);
        const int c0 = tid >> 7;
        const int kk = kidx_s[i];
        const float* crow = cb + kk * C_DIM;
        float lsum = 0.f;
        #pragma unroll
        for (int j = 0; j < 32; ++j) {
            int c = c0 * 32 + j;
            float q  = crow[c];
            float xv = xt_s[c][i];
            float d  = q - xv;
            lsum = fmaf(d, d, lsum);
            out[QUANT_OFF + ((b_img * C_DIM + c) << 10) + hw0 + i] = xv + d;
        }
        #pragma unroll
        for (int off = 32; off > 0; off >>= 1)
            lsum += __shfl_down(lsum, off, 64);
        if ((tid & 63) == 0)
            atomicAdd(ws_sum, (double)lsum);
    }
}

__global__ void vq_finalize(const double* __restrict__ ws_sum,
                            float* __restrict__ out)
{
    float m = (float)(ws_sum[0] / 4194304.0);
    out[LOSS_OFF]     = m;   // loss_embed
    out[LOSS_OFF + 1] = m;   // loss_commitment (identical forward value)
}

extern "C" void kernel_launch(void* const* d_in, const int* in_sizes, int n_in,
                              void* d_out, int out_size, void* d_ws, size_t ws_size,
                              hipStream_t stream) {
    const float* x  = (const float*)d_in[0];
    const float* cb = (const float*)d_in[1];
    float* out      = (float*)d_out;

    hipMemsetAsync(d_ws, 0, sizeof(double), stream);
    if (ws_size >= (size_t)WS_NEEDED) {
        vq_prep<<<400, 64, 0, stream>>>(cb, (float*)d_ws);
        vq_main<<<512, THREADS, 0, stream>>>(x, cb, (const float*)d_ws, out, (double*)d_ws);
    } else {
        vq_main_valu<<<512, THREADS, 0, stream>>>(x, cb, out, (double*)d_ws);
    }
    vq_finalize<<<1, 1, 0, stream>>>((const double*)d_ws, out);
}